// Round 14
// baseline (8520.792 us; speedup 1.0000x reference)
//
#include <hip/hip_runtime.h>

#define BATCH  64
#define TT     512
#define IDIM   64
#define HDIM   512
#define NAHEAD 24
#define HB     (HDIM * BATCH)

// ---- encoder_coop LDS layout: reduce scratch + bias ONLY ----
// Weights are now read via the SCALAR pipe (s_load into SGPRs): with
// wvu = readfirstlane(tid>>6) every weight address is provably uniform,
// so the compiler emits SMEM loads and v_fma takes the weight as its one
// SGPR operand. This removes the 104 ds_read_b128/thread/step LDS-delivery
// term (the round-12/13 floor) WITHOUT raising VGPR pressure (live ~45 regs
// vs the 4x-fatal spill cliff of r4/r7/r10/r11).
#define SCR_OFF    0                            // 16*64*17 = 17408
#define GL_OFF     17408                        // 16*64    = 1024
#define BIAS_OFF   18432                        // 16
#define ENC_SMEM_FLOATS 18448
#define ENC_SMEM_BYTES  (ENC_SMEM_FLOATS * 4)   // 73792 B

__device__ __forceinline__ float4 ld4(const float* p) {
  return *reinterpret_cast<const float4*>(p);
}
__device__ __forceinline__ float sigm(float x) { return 1.0f / (1.0f + expf(-x)); }

// Agent-scope write-through store for cross-WG data (readers on other XCDs;
// per-XCD L2s not coherent). Agent-scope LOADS bypass local L2 (~2x cost,
// round-8) — cross-step data is write-once and read with plain cached loads.
__device__ __forceinline__ void AS(float* p, float v) {
  __hip_atomic_store(p, v, __ATOMIC_RELAXED, __HIP_MEMORY_SCOPE_AGENT);
}

// ---------------------------------------------------------------------------
// ALL-SCAN flag barrier (round-13 verified at parity): every WG's wave-0
// scans all 256 flags; one fabric latency on the critical path. Flush-free.
// ---------------------------------------------------------------------------
__device__ __forceinline__ void flag_barrier(unsigned* flags, unsigned epoch,
                                             int bid) {
  asm volatile("s_waitcnt vmcnt(0)" ::: "memory");
  __syncthreads();
  if (threadIdx.x == 0)
    __hip_atomic_store(&flags[(size_t)bid * 16], epoch,
                       __ATOMIC_RELAXED, __HIP_MEMORY_SCOPE_AGENT);
  asm volatile("" ::: "memory");
  if (threadIdx.x < 64) {
    const int l = threadIdx.x;
    for (;;) {
      bool ok = true;
#pragma unroll
      for (int i = 0; i < 4; ++i) {
        unsigned v = __hip_atomic_load(&flags[(size_t)(l * 4 + i) * 16],
                                       __ATOMIC_RELAXED, __HIP_MEMORY_SCOPE_AGENT);
        ok &= (v >= epoch);
      }
      if (__all(ok)) break;
      __builtin_amdgcn_s_sleep(1);
    }
  }
  __syncthreads();
  asm volatile("" ::: "memory");
}

// 8 coalesced per-lane input loads (lane = batch); static indices only.
#define LD8(dst, base, off0)                                           \
  _Pragma("unroll") for (int i = 0; i < 8; ++i)                        \
    dst[i] = (base)[((off0) + i) * BATCH];

// Uniform weight-row pointer for gate-slot d: r(d) = (d>>1)*HDIM + j0 + (d&1).
#define WROW_H(mat, d) \
  ((mat) + (size_t)((((d) >> 1) * HDIM) + j0 + ((d) & 1)) * HDIM)

// Burn one 8-k seq0 chunk: a0 += v.whh0 (t<TT), a1 += v.wih1 (t>=1).
// Weight addrs uniform (kbs from readfirstlane) -> s_load, SGPR operands.
#define BURN_SEQ(v, C0)                                                       \
  do {                                                                        \
    if (t < TT) {                                                             \
      _Pragma("unroll") for (int d = 0; d < 8; ++d) {                         \
        const float* wp = WROW_H(w_hh0, d) + kbs + (C0);                      \
        float4 wa = ld4(wp), wb = ld4(wp + 4);                                \
        a0[d] += v[0]*wa.x + v[1]*wa.y + v[2]*wa.z + v[3]*wa.w                \
               + v[4]*wb.x + v[5]*wb.y + v[6]*wb.z + v[7]*wb.w;               \
      }                                                                       \
    }                                                                         \
    if (t >= 1) {                                                             \
      _Pragma("unroll") for (int d = 0; d < 8; ++d) {                         \
        const float* wp = WROW_H(w_ih1, d) + kbs + (C0);                      \
        float4 wa = ld4(wp), wb = ld4(wp + 4);                                \
        a1[d] += v[0]*wa.x + v[1]*wa.y + v[2]*wa.z + v[3]*wa.w                \
               + v[4]*wb.x + v[5]*wb.y + v[6]*wb.z + v[7]*wb.w;               \
      }                                                                       \
    }                                                                         \
  } while (0)

// Burn one 8-k enc chunk: a1 += v.whh1 (call under t>=1).
#define BURN_ENC(v, C0)                                                       \
  do {                                                                        \
    _Pragma("unroll") for (int d = 0; d < 8; ++d) {                           \
      const float* wp = WROW_H(w_hh1, d) + kbs + (C0);                        \
      float4 wa = ld4(wp), wb = ld4(wp + 4);                                  \
      a1[d] += v[0]*wa.x + v[1]*wa.y + v[2]*wa.z + v[3]*wa.w                  \
             + v[4]*wb.x + v[5]*wb.y + v[6]*wb.z + v[7]*wb.w;                 \
    }                                                                         \
  } while (0)

// ---------------------------------------------------------------------------
// Merged-cell encoder v8 (SMEM weights): 256 WGs x 1024 (1 WG/CU).
// Thread = (b = tid&63 -> one batch, wv = tid>>6 -> 32-k slice, wave-uniform
// via readfirstlane). 16 scalar accumulators (8 L0 + 8 L1 gate-slots).
// Inputs double-buffered in 8-k chunks (round-5 pattern). Reduce: scratch
// [16][64][17] (stride-17, 2-way banks = free), 1024-thread sum, 256-thread
// update, all-scan barrier — identical to the round-12/13 verified tail.
// ---------------------------------------------------------------------------
__global__ __launch_bounds__(1024, 4)
void encoder_coop(const float* __restrict__ xT,
                  const float* __restrict__ w_ih0, const float* __restrict__ w_hh0,
                  const float* __restrict__ b_ih0, const float* __restrict__ b_hh0,
                  const float* __restrict__ w_ih1, const float* __restrict__ w_hh1,
                  const float* __restrict__ b_ih1, const float* __restrict__ b_hh1,
                  float* __restrict__ seq0,        // [T+1][H][B], slot0 zero
                  float* __restrict__ enc,         // [T+1][H][B], slot0 zero
                  float* __restrict__ cst1,        // [H][B] final L1 c-state
                  unsigned* flags)
{
  extern __shared__ float smem[];
  const int tid = threadIdx.x;
  const int bid = blockIdx.x;
  const int j0  = bid * 2;
  const int b   = tid & 63;                      // lane = batch
  const int wv  = tid >> 6;                      // 0..15 (scratch slot)
  const int wvu = __builtin_amdgcn_readfirstlane(wv);  // provably uniform
  const int kbs = wvu * 32;                      // this wave's k-slice base

  if (tid < 16) {
    int d = tid & 7;
    size_t r = (size_t)((d >> 1) * HDIM + j0 + (d & 1));
    smem[BIAS_OFF + tid] = (tid < 8) ? (b_ih0[r] + b_hh0[r])
                                     : (b_ih1[r] + b_hh1[r]);
  }
  __syncthreads();

  float c0 = 0.f;                                // valid for tid < 128
  float c1 = 0.f;                                // valid for 128 <= tid < 256

  for (int t = 0; t <= TT; ++t) {
    const float* sp = seq0 + (size_t)t * HB + (size_t)kbs * BATCH + b;
    const float* ep = enc + (size_t)(t >= 1 ? t - 1 : 0) * HB
                          + (size_t)kbs * BATCH + b;

    float a0[8], a1[8];
#pragma unroll
    for (int d = 0; d < 8; ++d) { a0[d] = 0.f; a1[d] = 0.f; }

    float vA[8], vB[8];
    LD8(vA, sp, 0);
    LD8(vB, sp, 8);

    // ---- x-projection: 4 k per wave (16 waves x 4 = 64 = IDIM) ----
    if (t < TT) {
      const float* xp = xT + (size_t)t * IDIM * BATCH
                           + (size_t)(wvu * 4) * BATCH + b;
      float x0 = xp[0], x1 = xp[BATCH], x2 = xp[2 * BATCH], x3 = xp[3 * BATCH];
#pragma unroll
      for (int d = 0; d < 8; ++d) {
        const float* wp = w_ih0 +
            (size_t)(((d >> 1) * HDIM) + j0 + (d & 1)) * IDIM + wvu * 4;
        float4 w = ld4(wp);                      // uniform -> s_load
        a0[d] += x0 * w.x + x1 * w.y + x2 * w.z + x3 * w.w;
      }
    }

    // ---- pipelined 8-k chunks: issue next load, burn current ----
    BURN_SEQ(vA, 0);
    LD8(vA, sp, 16);
    BURN_SEQ(vB, 8);
    LD8(vB, sp, 24);
    BURN_SEQ(vA, 16);
    if (t >= 1) LD8(vA, ep, 0);
    BURN_SEQ(vB, 24);
    if (t >= 1) {
      LD8(vB, ep, 8);
      BURN_ENC(vA, 0);
      LD8(vA, ep, 16);
      BURN_ENC(vB, 8);
      LD8(vB, ep, 24);
      BURN_ENC(vA, 16);
      BURN_ENC(vB, 24);
    }

    // ---- REDUCE: 16 partials per dot, stride-17 scratch ----
#pragma unroll
    for (int d = 0; d < 8; ++d)
      smem[SCR_OFF + (d * 64 + b) * 17 + wv] = a0[d];
#pragma unroll
    for (int d = 0; d < 8; ++d)
      smem[SCR_OFF + ((8 + d) * 64 + b) * 17 + wv] = a1[d];
    __syncthreads();

    {                                            // all 1024: one (dd,bb) each
      const int dd = tid >> 6, bb = tid & 63;
      float s = 0.f;
#pragma unroll
      for (int i = 0; i < 16; ++i) s += smem[SCR_OFF + (dd * 64 + bb) * 17 + i];
      smem[GL_OFF + dd * 64 + bb] = s + smem[BIAS_OFF + dd];
    }
    __syncthreads();

    // ---- cell updates: u0,u1 = L0 cols; u2,u3 = L1 cols ----
    if (tid < 256) {
      const int bb = tid & 63, u = tid >> 6;
      if (u < 2) {
        if (t < TT) {
          const int cl = u;
          float gi = smem[GL_OFF + (0 + cl) * 64 + bb];
          float gf = smem[GL_OFF + (2 + cl) * 64 + bb];
          float gg = smem[GL_OFF + (4 + cl) * 64 + bb];
          float go = smem[GL_OFF + (6 + cl) * 64 + bb];
          float cn = sigm(gf) * c0 + sigm(gi) * tanhf(gg);
          float hn = sigm(go) * tanhf(cn);
          c0 = cn;
          AS(&seq0[(size_t)(t + 1) * HB + (size_t)(j0 + cl) * BATCH + bb], hn);
        }
      } else {
        if (t >= 1) {
          const int cl = u - 2;
          float gi = smem[GL_OFF + (8 + 0 + cl) * 64 + bb];
          float gf = smem[GL_OFF + (8 + 2 + cl) * 64 + bb];
          float gg = smem[GL_OFF + (8 + 4 + cl) * 64 + bb];
          float go = smem[GL_OFF + (8 + 6 + cl) * 64 + bb];
          float cn = sigm(gf) * c1 + sigm(gi) * tanhf(gg);
          float hn = sigm(go) * tanhf(cn);
          c1 = cn;
          AS(&enc[(size_t)t * HB + (size_t)(j0 + cl) * BATCH + bb], hn);
        }
      }
    }

    if (t < TT) flag_barrier(flags, (unsigned)(t + 1), bid);
  }

  if (tid >= 128 && tid < 256)
    cst1[(size_t)(j0 + ((tid >> 6) - 2)) * BATCH + (tid & 63)] = c1;
}

// ---------------------------------------------------------------------------
// Global-weight LSTM cell (decoder gates + encoder fallback).
// ---------------------------------------------------------------------------
template <int DIN0>
__device__ __forceinline__ void cell_tile2(
    int j0, const float* __restrict__ in0,
    const float* __restrict__ h_in,
    const float* __restrict__ w_ih,
    const float* __restrict__ w_hh,
    const float* __restrict__ b_ih, const float* __restrict__ b_hh,
    float* __restrict__ c_state,
    float* __restrict__ h_out,
    float* __restrict__ sm)
{
  const int tid = threadIdx.x;
  const int b  = tid & 63;
  const int ks = tid >> 6;
  constexpr int K  = DIN0 + HDIM;
  constexpr int KS = K / 16;
  const int k0 = ks * KS, k1 = k0 + KS;
  const int a0 = (k0 < DIN0) ? k0 : DIN0;
  const int a1 = (k1 < DIN0) ? k1 : DIN0;
  const int c0 = (k0 > DIN0) ? k0 - DIN0 : 0;
  const int c1 = (k1 > DIN0) ? k1 - DIN0 : 0;

  const float* wi = w_ih + (size_t)j0 * DIN0;
  const float* wh = w_hh + (size_t)j0 * HDIM;

  float acc[8] = {0.f, 0.f, 0.f, 0.f, 0.f, 0.f, 0.f, 0.f};

#pragma unroll 2
  for (int k = a0; k < a1; k += 4) {
    float x0 = in0[(k + 0) * BATCH + b];
    float x1 = in0[(k + 1) * BATCH + b];
    float x2 = in0[(k + 2) * BATCH + b];
    float x3 = in0[(k + 3) * BATCH + b];
#pragma unroll
    for (int d = 0; d < 8; ++d) {
      float4 w = ld4(wi + (size_t)((d >> 1) * HDIM + (d & 1)) * DIN0 + k);
      acc[d] += x0 * w.x + x1 * w.y + x2 * w.z + x3 * w.w;
    }
  }
#pragma unroll 2
  for (int k = c0; k < c1; k += 4) {
    float h0 = h_in[(k + 0) * BATCH + b];
    float h1 = h_in[(k + 1) * BATCH + b];
    float h2 = h_in[(k + 2) * BATCH + b];
    float h3 = h_in[(k + 3) * BATCH + b];
#pragma unroll
    for (int d = 0; d < 8; ++d) {
      float4 w = ld4(wh + (size_t)((d >> 1) * HDIM + (d & 1)) * HDIM + k);
      acc[d] += h0 * w.x + h1 * w.y + h2 * w.z + h3 * w.w;
    }
  }

  float* gl = sm + 8 * 64 * 17;
#pragma unroll
  for (int d = 0; d < 8; ++d) sm[(d * 64 + b) * 17 + ks] = acc[d];
  __syncthreads();

  if (tid < 512) {
    const int dd = tid >> 6, bb = tid & 63;
    float s = 0.f;
#pragma unroll
    for (int i = 0; i < 16; ++i) s += sm[(dd * 64 + bb) * 17 + i];
    const int r = (dd >> 1) * HDIM + j0 + (dd & 1);
    gl[dd * 64 + bb] = s + b_ih[r] + b_hh[r];
  }
  __syncthreads();

  if (tid < 128) {
    const int bb = tid & 63, cl = tid >> 6;
    const int jc = j0 + cl;
    float gi = gl[(0 + cl) * 64 + bb];
    float gf = gl[(2 + cl) * 64 + bb];
    float gg = gl[(4 + cl) * 64 + bb];
    float go = gl[(6 + cl) * 64 + bb];
    float cold = c_state[(size_t)jc * BATCH + bb];
    float cn = sigm(gf) * cold + sigm(gi) * tanhf(gg);
    float hn = sigm(go) * tanhf(cn);
    c_state[(size_t)jc * BATCH + bb] = cn;
    h_out[(size_t)jc * BATCH + bb] = hn;
  }
  __syncthreads();
}

// Fallback per-step kernel (only used if cooperative launch fails).
__global__ __launch_bounds__(1024, 1)
void lstm_step(int t,
               const float* __restrict__ xT,
               const float* __restrict__ w_ih0, const float* __restrict__ w_hh0,
               const float* __restrict__ b_ih0, const float* __restrict__ b_hh0,
               const float* __restrict__ w_ih1, const float* __restrict__ w_hh1,
               const float* __restrict__ b_ih1, const float* __restrict__ b_hh1,
               float* __restrict__ seq0, float* __restrict__ enc,
               float* __restrict__ cst0, float* __restrict__ cst1)
{
  __shared__ float sm[8 * 64 * 17 + 8 * 64];
  const int j0 = blockIdx.x * 2;
  if (t < TT)
    cell_tile2<IDIM>(j0, xT + (size_t)t * IDIM * BATCH,
                     seq0 + (size_t)t * HB,
                     w_ih0, w_hh0, b_ih0, b_hh0,
                     cst0, seq0 + (size_t)(t + 1) * HB, sm);
  if (t >= 1)
    cell_tile2<HDIM>(j0, seq0 + (size_t)t * HB,
                     enc + (size_t)(t - 1) * HB,
                     w_ih1, w_hh1, b_ih1, b_hh1,
                     cst1, enc + (size_t)t * HB, sm);
}

__global__ __launch_bounds__(1024, 1)
void dec_gates(const float* __restrict__ xi, const float* __restrict__ h_cur,
               const float* __restrict__ w_ih, const float* __restrict__ w_hh,
               const float* __restrict__ b_ih, const float* __restrict__ b_hh,
               float* __restrict__ cst, float* __restrict__ h_out)
{
  __shared__ float sm[8 * 64 * 17 + 8 * 64];
  cell_tile2<HDIM>(blockIdx.x * 2, xi, h_cur, w_ih, w_hh, b_ih, b_hh,
                   cst, h_out, sm);
}

__global__ __launch_bounds__(512, 2)
void attn_scores(const float* __restrict__ enc,
                 const float* __restrict__ h_cur,
                 float* __restrict__ scores)
{
  __shared__ float red[2][8][64];
  const int tid = threadIdx.x;
  const int b  = tid & 63;
  const int ks = tid >> 6;
  const int t0 = blockIdx.x * 2;
  const float* e0 = enc + (size_t)(t0 + 1) * HB + ks * 64 * BATCH;
  const float* e1 = e0 + HB;
  const float* hr = h_cur + ks * 64 * BATCH;
  float a0 = 0.f, a1 = 0.f;
#pragma unroll 4
  for (int k = 0; k < 64; ++k) {
    float hv = hr[k * BATCH + b];
    a0 += hv * e0[k * BATCH + b];
    a1 += hv * e1[k * BATCH + b];
  }
  red[0][ks][b] = a0;
  red[1][ks][b] = a1;
  __syncthreads();
  if (tid < 128) {
    int tl = tid >> 6;
    float s = 0.f;
#pragma unroll
    for (int i = 0; i < 8; ++i) s += red[tl][i][b];
    scores[(size_t)(t0 + tl) * BATCH + b] = s;
  }
}

__global__ __launch_bounds__(512, 2)
void attn_ctx(const float* __restrict__ enc,
              const float* __restrict__ scores,
              const float* __restrict__ h_cur,
              const float* __restrict__ w_fc, const float* __restrict__ b_fc,
              float* __restrict__ xi,
              float* __restrict__ out,
              int s)
{
  __shared__ float red[8][2][64];
  __shared__ float mz[2][64];
  __shared__ float ctxv[2][64];
  const int tid = threadIdx.x;
  const int b  = tid & 63;
  const int ts = tid >> 6;
  const int hc0 = blockIdx.x * 2;

  float m = -1e30f;
  for (int t = ts * 64; t < ts * 64 + 64; ++t)
    m = fmaxf(m, scores[(size_t)t * BATCH + b]);
  red[ts][0][b] = m;
  __syncthreads();
  if (tid < 64) {
    float mm = red[0][0][b];
#pragma unroll
    for (int i = 1; i < 8; ++i) mm = fmaxf(mm, red[i][0][b]);
    mz[0][b] = mm;
  }
  __syncthreads();
  m = mz[0][b];
  float z = 0.f;
  for (int t = ts * 64; t < ts * 64 + 64; ++t)
    z += expf(scores[(size_t)t * BATCH + b] - m);
  red[ts][1][b] = z;
  __syncthreads();
  if (tid < 64) {
    float zz = 0.f;
#pragma unroll
    for (int i = 0; i < 8; ++i) zz += red[i][1][b];
    mz[1][b] = 1.f / zz;
  }
  __syncthreads();
  const float rZ = mz[1][b];

  float a0 = 0.f, a1 = 0.f;
  const float* eb = enc + HB + (size_t)hc0 * BATCH + b;
  for (int t = ts * 64; t < ts * 64 + 64; ++t) {
    float p = expf(scores[(size_t)t * BATCH + b] - m) * rZ;
    a0 += p * eb[(size_t)t * HB];
    a1 += p * eb[(size_t)t * HB + BATCH];
  }
  __syncthreads();
  red[ts][0][b] = a0;
  red[ts][1][b] = a1;
  __syncthreads();
  if (tid < 128) {
    int cl = tid >> 6;
    float c = 0.f;
#pragma unroll
    for (int i = 0; i < 8; ++i) c += red[i][cl][b];
    ctxv[cl][b] = c;
  }

  float p0 = 0.f, p1 = 0.f;
  if (s >= 1) {
    const float* w0 = w_fc + (size_t)hc0 * HDIM + ts * 64;
    const float* w1 = w0 + HDIM;
    const float* hr = h_cur + ts * 64 * BATCH;
#pragma unroll 2
    for (int k = 0; k < 64; k += 4) {
      float4 wa = ld4(w0 + k), wb = ld4(w1 + k);
      float h0 = hr[(k + 0) * BATCH + b], h1 = hr[(k + 1) * BATCH + b];
      float h2 = hr[(k + 2) * BATCH + b], h3 = hr[(k + 3) * BATCH + b];
      p0 += wa.x * h0 + wa.y * h1 + wa.z * h2 + wa.w * h3;
      p1 += wb.x * h0 + wb.y * h1 + wb.z * h2 + wb.w * h3;
    }
  }
  __syncthreads();
  red[ts][0][b] = p0;
  red[ts][1][b] = p1;
  __syncthreads();
  if (tid < 128) {
    int cl = tid >> 6;
    int cc = hc0 + cl;
    float pred = 0.f;
    if (s >= 1) {
#pragma unroll
      for (int i = 0; i < 8; ++i) pred += red[i][cl][b];
      pred += b_fc[cc];
      out[((size_t)b * NAHEAD + (s - 1)) * HDIM + cc] = pred;
    }
    xi[(size_t)cc * BATCH + b] = ctxv[cl][b] + pred;
  }
}

__global__ __launch_bounds__(512, 2)
void fc_out(const float* __restrict__ h, const float* __restrict__ w_fc,
            const float* __restrict__ b_fc, float* __restrict__ out, int srow)
{
  __shared__ float red[8][2][64];
  const int tid = threadIdx.x;
  const int b  = tid & 63;
  const int ks = tid >> 6;
  const int cc0 = blockIdx.x * 2;
  const float* w0 = w_fc + (size_t)cc0 * HDIM + ks * 64;
  const float* w1 = w0 + HDIM;
  const float* hr = h + ks * 64 * BATCH;
  float p0 = 0.f, p1 = 0.f;
#pragma unroll 2
  for (int k = 0; k < 64; k += 4) {
    float4 wa = ld4(w0 + k), wb = ld4(w1 + k);
    float h0 = hr[(k + 0) * BATCH + b], h1 = hr[(k + 1) * BATCH + b];
    float h2 = hr[(k + 2) * BATCH + b], h3 = hr[(k + 3) * BATCH + b];
    p0 += wa.x * h0 + wa.y * h1 + wa.z * h2 + wa.w * h3;
    p1 += wb.x * h0 + wb.y * h1 + wb.z * h2 + wb.w * h3;
  }
  red[ks][0][b] = p0;
  red[ks][1][b] = p1;
  __syncthreads();
  if (tid < 128) {
    int cl = tid >> 6;
    int cc = cc0 + cl;
    float p = 0.f;
#pragma unroll
    for (int i = 0; i < 8; ++i) p += red[i][cl][b];
    out[((size_t)b * NAHEAD + srow) * HDIM + cc] = p + b_fc[cc];
  }
}

__global__ __launch_bounds__(256)
void transpose_x(const float* __restrict__ x, float* __restrict__ xT)
{
  __shared__ float tile[64][65];
  const int t = blockIdx.x;
  const int lane = threadIdx.x & 63;
  const int w    = threadIdx.x >> 6;
#pragma unroll
  for (int ii = 0; ii < 16; ++ii) {
    int b = w * 16 + ii;
    tile[b][lane] = x[((size_t)b * TT + t) * IDIM + lane];
  }
  __syncthreads();
#pragma unroll
  for (int ii = 0; ii < 16; ++ii) {
    int i = w * 16 + ii;
    xT[((size_t)t * IDIM + i) * BATCH + lane] = tile[lane][i];
  }
}

// ---------------------------------------------------------------------------
extern "C" void kernel_launch(void* const* d_in, const int* in_sizes, int n_in,
                              void* d_out, int out_size, void* d_ws, size_t ws_size,
                              hipStream_t stream) {
  const float* x     = (const float*)d_in[0];
  const float* w_ih0 = (const float*)d_in[1];
  const float* w_hh0 = (const float*)d_in[2];
  const float* b_ih0 = (const float*)d_in[3];
  const float* b_hh0 = (const float*)d_in[4];
  const float* w_ih1 = (const float*)d_in[5];
  const float* w_hh1 = (const float*)d_in[6];
  const float* b_ih1 = (const float*)d_in[7];
  const float* b_hh1 = (const float*)d_in[8];
  const float* w_ihd = (const float*)d_in[9];
  const float* w_hhd = (const float*)d_in[10];
  const float* b_ihd = (const float*)d_in[11];
  const float* b_hhd = (const float*)d_in[12];
  const float* w_fc  = (const float*)d_in[13];
  const float* b_fc  = (const float*)d_in[14];
  float* out = (float*)d_out;

  char* ws = (char*)d_ws;
  size_t off = 0;
  auto alloc = [&](size_t bytes) -> void* {
    void* p = ws + off;
    off += (bytes + 255) & ~(size_t)255;
    return p;
  };

  float* cst0 = (float*)alloc((size_t)HB * 4);            // zero (fallback)
  float* cst1 = (float*)alloc((size_t)HB * 4);            // final L1 c-state
  float* seq0 = (float*)alloc((size_t)(TT + 1) * HB * 4); // slot0 zero
  float* enc  = (float*)alloc((size_t)(TT + 1) * HB * 4); // slot0 zero
  float* xT   = (float*)alloc((size_t)TT * IDIM * BATCH * 4);
  float* scores = (float*)alloc((size_t)TT * BATCH * 4);
  float* xi     = (float*)alloc((size_t)HB * 4);
  float* hdec   = (float*)alloc((size_t)2 * HB * 4);
  unsigned* flags   = (unsigned*)alloc(256 * 16 * 4);     // encoder barrier
  (void)ws_size; (void)in_sizes; (void)n_in; (void)out_size;

  hipMemsetAsync(cst0, 0, (size_t)HB * 4 * 2, stream);    // cst0+cst1
  hipMemsetAsync(seq0, 0, (size_t)HB * 4, stream);
  hipMemsetAsync(enc,  0, (size_t)HB * 4, stream);
  hipMemsetAsync(flags, 0, 256 * 16 * 4, stream);

  transpose_x<<<TT, 256, 0, stream>>>(x, xT);

  static bool attr_set = false;
  if (!attr_set) {
    hipFuncSetAttribute(reinterpret_cast<const void*>(encoder_coop),
                        hipFuncAttributeMaxDynamicSharedMemorySize,
                        ENC_SMEM_BYTES);
    attr_set = true;
  }

  // ---- encoder: ONE cooperative kernel (SMEM-weight variant) ----
  void* args[] = {
    (void*)&xT,
    (void*)&w_ih0, (void*)&w_hh0, (void*)&b_ih0, (void*)&b_hh0,
    (void*)&w_ih1, (void*)&w_hh1, (void*)&b_ih1, (void*)&b_hh1,
    (void*)&seq0, (void*)&enc, (void*)&cst1, (void*)&flags
  };
  hipError_t cerr = hipLaunchCooperativeKernel(
      reinterpret_cast<void*>(encoder_coop), dim3(256), dim3(1024),
      args, (unsigned)ENC_SMEM_BYTES, stream);
  if (cerr != hipSuccess) {
    for (int t = 0; t <= TT; ++t) {
      lstm_step<<<256, 1024, 0, stream>>>(
          t, xT, w_ih0, w_hh0, b_ih0, b_hh0,
          w_ih1, w_hh1, b_ih1, b_hh1, seq0, enc, cst0, cst1);
    }
  }

  // ---- decoder: launch-based chain (round-6/12 verified: ~0.75 ms) ----
  const float* h_cur = enc + (size_t)TT * HB;
  for (int s = 0; s < NAHEAD; ++s) {
    attn_scores<<<256, 512, 0, stream>>>(enc, h_cur, scores);
    attn_ctx<<<256, 512, 0, stream>>>(enc, scores, h_cur, w_fc, b_fc,
                                      xi, out, s);
    float* h_nxt = hdec + (size_t)(s & 1) * HB;
    dec_gates<<<256, 1024, 0, stream>>>(xi, h_cur, w_ihd, w_hhd,
                                        b_ihd, b_hhd, cst1, h_nxt);
    h_cur = h_nxt;
  }
  fc_out<<<256, 512, 0, stream>>>(h_cur, w_fc, b_fc, out, NAHEAD - 1);
}

// Round 15
// 7161.681 us; speedup vs baseline: 1.1898x; 1.1898x over previous
//
#include <hip/hip_runtime.h>

#define BATCH  64
#define TT     512
#define IDIM   64
#define HDIM   512
#define NAHEAD 24
#define HB     (HDIM * BATCH)

// ---- encoder_coop LDS layout (float offsets into extern smem[]) ----
// THE stable operating point (verified rounds 6/8/9/12: VGPR 64, zero spill,
// encoder 6.45-6.5 ms). Every deviation measured worse:
//   r4  monolithic 64-reg stage  -> spill, 42 GB scratch traffic
//   r7  r=4 batch quads          -> spill, 250 GB
//   r10 global-weight burns      -> spill, 45 GB
//   r11 launch_bounds(1024,8)    -> VGPR forced to 32, spill, 39 GB
//   r13 all-scan barrier         -> parity (barrier already latency-minimal)
//   r14 SMEM (scalar-pipe) wts   -> +1 ms (r=1 mapping doubles traffic;
//                                   r=2 reuse and uniformity are exclusive)
#define WIH0_OFF   0                            // 8*64   = 512
#define WHH0_OFF   512                          // 8*512  = 4096
#define WIH1_OFF   4608
#define WHH1_OFF   8704
#define SCR_OFF    12800                        // 16*64*17 = 17408
#define GL_OFF     30208                        // 16*64    = 1024
#define BIAS_OFF   31232                        // 16
#define ENC_SMEM_FLOATS 31248
#define ENC_SMEM_BYTES  (ENC_SMEM_FLOATS * 4)   // 124992 B < 160 KiB

typedef float v2f __attribute__((ext_vector_type(2)));

__device__ __forceinline__ float4 ld4(const float* p) {
  return *reinterpret_cast<const float4*>(p);
}
__device__ __forceinline__ float sigm(float x) { return 1.0f / (1.0f + expf(-x)); }

// Agent-scope write-through store for cross-WG data (readers on other XCDs;
// per-XCD L2s not coherent). Agent-scope LOADS bypass local L2 (~2x cost,
// round-8) — cross-step data is write-once and read with plain cached loads.
__device__ __forceinline__ void AS(float* p, float v) {
  __hip_atomic_store(p, v, __ATOMIC_RELAXED, __HIP_MEMORY_SCOPE_AGENT);
}

// ---------------------------------------------------------------------------
// Flag-array grid barrier (flush-free, RMW-free arrivals). No cache
// maintenance (cg::grid.sync's per-step L2 flush was the round-1 regression).
// Cross-step data is agent-scope stored + vmcnt-drained before the flag
// store, and only read next epoch — no stale L2 copy can exist.
// ---------------------------------------------------------------------------
__device__ __forceinline__ void flag_barrier(unsigned* flags, unsigned* release,
                                             unsigned epoch, int bid) {
  asm volatile("s_waitcnt vmcnt(0)" ::: "memory");
  __syncthreads();
  if (threadIdx.x == 0)
    __hip_atomic_store(&flags[(size_t)bid * 16], epoch,
                       __ATOMIC_RELAXED, __HIP_MEMORY_SCOPE_AGENT);
  asm volatile("" ::: "memory");
  if (bid == 0 && threadIdx.x < 64) {
    const int l = threadIdx.x;
    for (;;) {
      bool ok = true;
#pragma unroll
      for (int i = 0; i < 4; ++i) {
        unsigned v = __hip_atomic_load(&flags[(size_t)(l * 4 + i) * 16],
                                       __ATOMIC_RELAXED, __HIP_MEMORY_SCOPE_AGENT);
        ok &= (v >= epoch);
      }
      if (__all(ok)) break;
      __builtin_amdgcn_s_sleep(1);
    }
    if (threadIdx.x == 0)
      __hip_atomic_store(release, epoch, __ATOMIC_RELAXED,
                         __HIP_MEMORY_SCOPE_AGENT);
  }
  if (threadIdx.x == 0) {
    while (__hip_atomic_load(release, __ATOMIC_RELAXED,
                             __HIP_MEMORY_SCOPE_AGENT) < epoch)
      __builtin_amdgcn_s_sleep(1);
  }
  __syncthreads();
  asm volatile("" ::: "memory");
}

// Stage 8 k-elements for 2 batches (bp, bp+32) as v2f; static indices only.
#define STG8(dst, base, off0)                                          \
  _Pragma("unroll") for (int i = 0; i < 8; ++i) {                      \
    dst[i].x = (base)[((off0) + i) * BATCH];                           \
    dst[i].y = (base)[((off0) + i) * BATCH + 32];                      \
  }

#define BURN_S(sarr, C0)                                                      \
  do {                                                                        \
    _Pragma("unroll") for (int c = 0; c < 8; c += 4) {                        \
      if (t < TT) {                                                           \
        _Pragma("unroll") for (int d = 0; d < 8; ++d) {                       \
          float4 w = ld4(&smem[WHH0_OFF + d * HDIM + ks * 16 + (C0) + c]);    \
          a0[d] += sarr[c]*w.x + sarr[c+1]*w.y + sarr[c+2]*w.z + sarr[c+3]*w.w;\
        }                                                                     \
      }                                                                       \
      if (t >= 1) {                                                           \
        _Pragma("unroll") for (int d = 0; d < 8; ++d) {                       \
          float4 w = ld4(&smem[WIH1_OFF + d * HDIM + ks * 16 + (C0) + c]);    \
          a1[d] += sarr[c]*w.x + sarr[c+1]*w.y + sarr[c+2]*w.z + sarr[c+3]*w.w;\
        }                                                                     \
      }                                                                       \
    }                                                                         \
  } while (0)

#define BURN_E(earr, C0)                                                      \
  do {                                                                        \
    if (t >= 1) {                                                             \
      _Pragma("unroll") for (int c = 0; c < 8; c += 4) {                      \
        _Pragma("unroll") for (int d = 0; d < 8; ++d) {                       \
          float4 w = ld4(&smem[WHH1_OFF + d * HDIM + ks * 16 + (C0) + c]);    \
          a1[d] += earr[c]*w.x + earr[c+1]*w.y + earr[c+2]*w.z + earr[c+3]*w.w;\
        }                                                                     \
      }                                                                       \
    }                                                                         \
  } while (0)

// ---------------------------------------------------------------------------
// Merged-cell encoder (round-6/9/12 verified): 256 WGs x 1024 (1 WG/CU),
// r=2 batch pairs, LDS weights, shfl merge, stride-17 scratch, 1 barrier/step.
// ---------------------------------------------------------------------------
__global__ __launch_bounds__(1024, 4)
void encoder_coop(const float* __restrict__ xT,
                  const float* __restrict__ w_ih0, const float* __restrict__ w_hh0,
                  const float* __restrict__ b_ih0, const float* __restrict__ b_hh0,
                  const float* __restrict__ w_ih1, const float* __restrict__ w_hh1,
                  const float* __restrict__ b_ih1, const float* __restrict__ b_hh1,
                  float* __restrict__ seq0,        // [T+1][H][B], slot0 zero
                  float* __restrict__ enc,         // [T+1][H][B], slot0 zero
                  float* __restrict__ cst1,        // [H][B] final L1 c-state
                  unsigned* flags, unsigned* release)
{
  extern __shared__ float smem[];
  const int tid  = threadIdx.x;
  const int bid  = blockIdx.x;
  const int j0   = bid * 2;
  const int lane = tid & 63;
  const int wv   = tid >> 6;                     // 0..15 (scratch slot)
  const int bp   = tid & 31;                     // batch pair {bp, bp+32}
  const int ks   = tid >> 5;                     // 0..31 (k-slice of 16)

  for (int idx = tid; idx < 8 * IDIM; idx += 1024) {
    int d = idx >> 6, k = idx & 63;
    size_t r = (size_t)((d >> 1) * HDIM + j0 + (d & 1));
    smem[WIH0_OFF + idx] = w_ih0[r * IDIM + k];
  }
  for (int idx = tid; idx < 8 * HDIM; idx += 1024) {
    int d = idx >> 9, k = idx & 511;
    size_t r = (size_t)((d >> 1) * HDIM + j0 + (d & 1));
    smem[WHH0_OFF + idx] = w_hh0[r * HDIM + k];
    smem[WIH1_OFF + idx] = w_ih1[r * HDIM + k];
    smem[WHH1_OFF + idx] = w_hh1[r * HDIM + k];
  }
  if (tid < 16) {
    int d = tid & 7;
    size_t r = (size_t)((d >> 1) * HDIM + j0 + (d & 1));
    smem[BIAS_OFF + tid] = (tid < 8) ? (b_ih0[r] + b_hh0[r])
                                     : (b_ih1[r] + b_hh1[r]);
  }
  __syncthreads();

  float c0 = 0.f;                                // valid for tid < 128
  float c1 = 0.f;                                // valid for 128 <= tid < 256

  for (int t = 0; t <= TT; ++t) {
    const float* sp = seq0 + (size_t)t * HB + (size_t)(ks * 16) * BATCH + bp;
    const float* ep = enc + (size_t)(t >= 1 ? t - 1 : 0) * HB
                          + (size_t)(ks * 16) * BATCH + bp;

    v2f sA[8], sB[8], eA[8], eB[8];
    v2f xv[4];

    STG8(sA, sp, 0);
    STG8(sB, sp, 8);
    if (t < TT && ks < 16) {
      const float* xp = xT + (size_t)t * IDIM * BATCH
                           + (size_t)(ks * 4) * BATCH + bp;
#pragma unroll
      for (int i = 0; i < 4; ++i) {
        xv[i].x = xp[i * BATCH];
        xv[i].y = xp[i * BATCH + 32];
      }
    }

    v2f a0[8], a1[8];
#pragma unroll
    for (int d = 0; d < 8; ++d) { a0[d] = 0.f; a1[d] = 0.f; }

    if (t < TT && ks < 16) {
#pragma unroll
      for (int d = 0; d < 8; ++d) {
        float4 w = ld4(&smem[WIH0_OFF + d * IDIM + ks * 4]);
        a0[d] += xv[0]*w.x + xv[1]*w.y + xv[2]*w.z + xv[3]*w.w;
      }
    }

    BURN_S(sA, 0);
    if (t >= 1) STG8(eA, ep, 0);
    BURN_S(sB, 8);
    if (t >= 1) STG8(eB, ep, 8);
    BURN_E(eA, 0);
    BURN_E(eB, 8);

#pragma unroll
    for (int d = 0; d < 8; ++d) {
      float m0x = a0[d].x + __shfl_xor(a0[d].x, 32);
      float m0y = a0[d].y + __shfl_xor(a0[d].y, 32);
      smem[SCR_OFF + (d * 64 + lane) * 17 + wv] = (lane >= 32) ? m0y : m0x;
      float m1x = a1[d].x + __shfl_xor(a1[d].x, 32);
      float m1y = a1[d].y + __shfl_xor(a1[d].y, 32);
      smem[SCR_OFF + ((8 + d) * 64 + lane) * 17 + wv] = (lane >= 32) ? m1y : m1x;
    }
    __syncthreads();

    {
      const int dd = tid >> 6, bb = tid & 63;
      float s = 0.f;
#pragma unroll
      for (int i = 0; i < 16; ++i) s += smem[SCR_OFF + (dd * 64 + bb) * 17 + i];
      smem[GL_OFF + dd * 64 + bb] = s + smem[BIAS_OFF + dd];
    }
    __syncthreads();

    if (tid < 256) {
      const int bb = tid & 63, u = tid >> 6;
      if (u < 2) {
        if (t < TT) {
          const int cl = u;
          float gi = smem[GL_OFF + (0 + cl) * 64 + bb];
          float gf = smem[GL_OFF + (2 + cl) * 64 + bb];
          float gg = smem[GL_OFF + (4 + cl) * 64 + bb];
          float go = smem[GL_OFF + (6 + cl) * 64 + bb];
          float cn = sigm(gf) * c0 + sigm(gi) * tanhf(gg);
          float hn = sigm(go) * tanhf(cn);
          c0 = cn;
          AS(&seq0[(size_t)(t + 1) * HB + (size_t)(j0 + cl) * BATCH + bb], hn);
        }
      } else {
        if (t >= 1) {
          const int cl = u - 2;
          float gi = smem[GL_OFF + (8 + 0 + cl) * 64 + bb];
          float gf = smem[GL_OFF + (8 + 2 + cl) * 64 + bb];
          float gg = smem[GL_OFF + (8 + 4 + cl) * 64 + bb];
          float go = smem[GL_OFF + (8 + 6 + cl) * 64 + bb];
          float cn = sigm(gf) * c1 + sigm(gi) * tanhf(gg);
          float hn = sigm(go) * tanhf(cn);
          c1 = cn;
          AS(&enc[(size_t)t * HB + (size_t)(j0 + cl) * BATCH + bb], hn);
        }
      }
    }

    if (t < TT) flag_barrier(flags, release, (unsigned)(t + 1), bid);
  }

  if (tid >= 128 && tid < 256)
    cst1[(size_t)(j0 + ((tid >> 6) - 2)) * BATCH + (tid & 63)] = c1;
}

// ---------------------------------------------------------------------------
// Global-weight LSTM cell (decoder gates + encoder fallback).
// ---------------------------------------------------------------------------
template <int DIN0>
__device__ __forceinline__ void cell_tile2(
    int j0, const float* __restrict__ in0,
    const float* __restrict__ h_in,
    const float* __restrict__ w_ih,
    const float* __restrict__ w_hh,
    const float* __restrict__ b_ih, const float* __restrict__ b_hh,
    float* __restrict__ c_state,
    float* __restrict__ h_out,
    float* __restrict__ sm)
{
  const int tid = threadIdx.x;
  const int b  = tid & 63;
  const int ks = tid >> 6;
  constexpr int K  = DIN0 + HDIM;
  constexpr int KS = K / 16;
  const int k0 = ks * KS, k1 = k0 + KS;
  const int a0 = (k0 < DIN0) ? k0 : DIN0;
  const int a1 = (k1 < DIN0) ? k1 : DIN0;
  const int c0 = (k0 > DIN0) ? k0 - DIN0 : 0;
  const int c1 = (k1 > DIN0) ? k1 - DIN0 : 0;

  const float* wi = w_ih + (size_t)j0 * DIN0;
  const float* wh = w_hh + (size_t)j0 * HDIM;

  float acc[8] = {0.f, 0.f, 0.f, 0.f, 0.f, 0.f, 0.f, 0.f};

#pragma unroll 2
  for (int k = a0; k < a1; k += 4) {
    float x0 = in0[(k + 0) * BATCH + b];
    float x1 = in0[(k + 1) * BATCH + b];
    float x2 = in0[(k + 2) * BATCH + b];
    float x3 = in0[(k + 3) * BATCH + b];
#pragma unroll
    for (int d = 0; d < 8; ++d) {
      float4 w = ld4(wi + (size_t)((d >> 1) * HDIM + (d & 1)) * DIN0 + k);
      acc[d] += x0 * w.x + x1 * w.y + x2 * w.z + x3 * w.w;
    }
  }
#pragma unroll 2
  for (int k = c0; k < c1; k += 4) {
    float h0 = h_in[(k + 0) * BATCH + b];
    float h1 = h_in[(k + 1) * BATCH + b];
    float h2 = h_in[(k + 2) * BATCH + b];
    float h3 = h_in[(k + 3) * BATCH + b];
#pragma unroll
    for (int d = 0; d < 8; ++d) {
      float4 w = ld4(wh + (size_t)((d >> 1) * HDIM + (d & 1)) * HDIM + k);
      acc[d] += h0 * w.x + h1 * w.y + h2 * w.z + h3 * w.w;
    }
  }

  float* gl = sm + 8 * 64 * 17;
#pragma unroll
  for (int d = 0; d < 8; ++d) sm[(d * 64 + b) * 17 + ks] = acc[d];
  __syncthreads();

  if (tid < 512) {
    const int dd = tid >> 6, bb = tid & 63;
    float s = 0.f;
#pragma unroll
    for (int i = 0; i < 16; ++i) s += sm[(dd * 64 + bb) * 17 + i];
    const int r = (dd >> 1) * HDIM + j0 + (dd & 1);
    gl[dd * 64 + bb] = s + b_ih[r] + b_hh[r];
  }
  __syncthreads();

  if (tid < 128) {
    const int bb = tid & 63, cl = tid >> 6;
    const int jc = j0 + cl;
    float gi = gl[(0 + cl) * 64 + bb];
    float gf = gl[(2 + cl) * 64 + bb];
    float gg = gl[(4 + cl) * 64 + bb];
    float go = gl[(6 + cl) * 64 + bb];
    float cold = c_state[(size_t)jc * BATCH + bb];
    float cn = sigm(gf) * cold + sigm(gi) * tanhf(gg);
    float hn = sigm(go) * tanhf(cn);
    c_state[(size_t)jc * BATCH + bb] = cn;
    h_out[(size_t)jc * BATCH + bb] = hn;
  }
  __syncthreads();
}

// Fallback per-step kernel (only used if cooperative launch fails).
__global__ __launch_bounds__(1024, 1)
void lstm_step(int t,
               const float* __restrict__ xT,
               const float* __restrict__ w_ih0, const float* __restrict__ w_hh0,
               const float* __restrict__ b_ih0, const float* __restrict__ b_hh0,
               const float* __restrict__ w_ih1, const float* __restrict__ w_hh1,
               const float* __restrict__ b_ih1, const float* __restrict__ b_hh1,
               float* __restrict__ seq0, float* __restrict__ enc,
               float* __restrict__ cst0, float* __restrict__ cst1)
{
  __shared__ float sm[8 * 64 * 17 + 8 * 64];
  const int j0 = blockIdx.x * 2;
  if (t < TT)
    cell_tile2<IDIM>(j0, xT + (size_t)t * IDIM * BATCH,
                     seq0 + (size_t)t * HB,
                     w_ih0, w_hh0, b_ih0, b_hh0,
                     cst0, seq0 + (size_t)(t + 1) * HB, sm);
  if (t >= 1)
    cell_tile2<HDIM>(j0, seq0 + (size_t)t * HB,
                     enc + (size_t)(t - 1) * HB,
                     w_ih1, w_hh1, b_ih1, b_hh1,
                     cst1, enc + (size_t)t * HB, sm);
}

__global__ __launch_bounds__(1024, 1)
void dec_gates(const float* __restrict__ xi, const float* __restrict__ h_cur,
               const float* __restrict__ w_ih, const float* __restrict__ w_hh,
               const float* __restrict__ b_ih, const float* __restrict__ b_hh,
               float* __restrict__ cst, float* __restrict__ h_out)
{
  __shared__ float sm[8 * 64 * 17 + 8 * 64];
  cell_tile2<HDIM>(blockIdx.x * 2, xi, h_cur, w_ih, w_hh, b_ih, b_hh,
                   cst, h_out, sm);
}

__global__ __launch_bounds__(512, 2)
void attn_scores(const float* __restrict__ enc,
                 const float* __restrict__ h_cur,
                 float* __restrict__ scores)
{
  __shared__ float red[2][8][64];
  const int tid = threadIdx.x;
  const int b  = tid & 63;
  const int ks = tid >> 6;
  const int t0 = blockIdx.x * 2;
  const float* e0 = enc + (size_t)(t0 + 1) * HB + ks * 64 * BATCH;
  const float* e1 = e0 + HB;
  const float* hr = h_cur + ks * 64 * BATCH;
  float a0 = 0.f, a1 = 0.f;
#pragma unroll 4
  for (int k = 0; k < 64; ++k) {
    float hv = hr[k * BATCH + b];
    a0 += hv * e0[k * BATCH + b];
    a1 += hv * e1[k * BATCH + b];
  }
  red[0][ks][b] = a0;
  red[1][ks][b] = a1;
  __syncthreads();
  if (tid < 128) {
    int tl = tid >> 6;
    float s = 0.f;
#pragma unroll
    for (int i = 0; i < 8; ++i) s += red[tl][i][b];
    scores[(size_t)(t0 + tl) * BATCH + b] = s;
  }
}

__global__ __launch_bounds__(512, 2)
void attn_ctx(const float* __restrict__ enc,
              const float* __restrict__ scores,
              const float* __restrict__ h_cur,
              const float* __restrict__ w_fc, const float* __restrict__ b_fc,
              float* __restrict__ xi,
              float* __restrict__ out,
              int s)
{
  __shared__ float red[8][2][64];
  __shared__ float mz[2][64];
  __shared__ float ctxv[2][64];
  const int tid = threadIdx.x;
  const int b  = tid & 63;
  const int ts = tid >> 6;
  const int hc0 = blockIdx.x * 2;

  float m = -1e30f;
  for (int t = ts * 64; t < ts * 64 + 64; ++t)
    m = fmaxf(m, scores[(size_t)t * BATCH + b]);
  red[ts][0][b] = m;
  __syncthreads();
  if (tid < 64) {
    float mm = red[0][0][b];
#pragma unroll
    for (int i = 1; i < 8; ++i) mm = fmaxf(mm, red[i][0][b]);
    mz[0][b] = mm;
  }
  __syncthreads();
  m = mz[0][b];
  float z = 0.f;
  for (int t = ts * 64; t < ts * 64 + 64; ++t)
    z += expf(scores[(size_t)t * BATCH + b] - m);
  red[ts][1][b] = z;
  __syncthreads();
  if (tid < 64) {
    float zz = 0.f;
#pragma unroll
    for (int i = 0; i < 8; ++i) zz += red[i][1][b];
    mz[1][b] = 1.f / zz;
  }
  __syncthreads();
  const float rZ = mz[1][b];

  float a0 = 0.f, a1 = 0.f;
  const float* eb = enc + HB + (size_t)hc0 * BATCH + b;
  for (int t = ts * 64; t < ts * 64 + 64; ++t) {
    float p = expf(scores[(size_t)t * BATCH + b] - m) * rZ;
    a0 += p * eb[(size_t)t * HB];
    a1 += p * eb[(size_t)t * HB + BATCH];
  }
  __syncthreads();
  red[ts][0][b] = a0;
  red[ts][1][b] = a1;
  __syncthreads();
  if (tid < 128) {
    int cl = tid >> 6;
    float c = 0.f;
#pragma unroll
    for (int i = 0; i < 8; ++i) c += red[i][cl][b];
    ctxv[cl][b] = c;
  }

  float p0 = 0.f, p1 = 0.f;
  if (s >= 1) {
    const float* w0 = w_fc + (size_t)hc0 * HDIM + ts * 64;
    const float* w1 = w0 + HDIM;
    const float* hr = h_cur + ts * 64 * BATCH;
#pragma unroll 2
    for (int k = 0; k < 64; k += 4) {
      float4 wa = ld4(w0 + k), wb = ld4(w1 + k);
      float h0 = hr[(k + 0) * BATCH + b], h1 = hr[(k + 1) * BATCH + b];
      float h2 = hr[(k + 2) * BATCH + b], h3 = hr[(k + 3) * BATCH + b];
      p0 += wa.x * h0 + wa.y * h1 + wa.z * h2 + wa.w * h3;
      p1 += wb.x * h0 + wb.y * h1 + wb.z * h2 + wb.w * h3;
    }
  }
  __syncthreads();
  red[ts][0][b] = p0;
  red[ts][1][b] = p1;
  __syncthreads();
  if (tid < 128) {
    int cl = tid >> 6;
    int cc = hc0 + cl;
    float pred = 0.f;
    if (s >= 1) {
#pragma unroll
      for (int i = 0; i < 8; ++i) pred += red[i][cl][b];
      pred += b_fc[cc];
      out[((size_t)b * NAHEAD + (s - 1)) * HDIM + cc] = pred;
    }
    xi[(size_t)cc * BATCH + b] = ctxv[cl][b] + pred;
  }
}

__global__ __launch_bounds__(512, 2)
void fc_out(const float* __restrict__ h, const float* __restrict__ w_fc,
            const float* __restrict__ b_fc, float* __restrict__ out, int srow)
{
  __shared__ float red[8][2][64];
  const int tid = threadIdx.x;
  const int b  = tid & 63;
  const int ks = tid >> 6;
  const int cc0 = blockIdx.x * 2;
  const float* w0 = w_fc + (size_t)cc0 * HDIM + ks * 64;
  const float* w1 = w0 + HDIM;
  const float* hr = h + ks * 64 * BATCH;
  float p0 = 0.f, p1 = 0.f;
#pragma unroll 2
  for (int k = 0; k < 64; k += 4) {
    float4 wa = ld4(w0 + k), wb = ld4(w1 + k);
    float h0 = hr[(k + 0) * BATCH + b], h1 = hr[(k + 1) * BATCH + b];
    float h2 = hr[(k + 2) * BATCH + b], h3 = hr[(k + 3) * BATCH + b];
    p0 += wa.x * h0 + wa.y * h1 + wa.z * h2 + wa.w * h3;
    p1 += wb.x * h0 + wb.y * h1 + wb.z * h2 + wb.w * h3;
  }
  red[ks][0][b] = p0;
  red[ks][1][b] = p1;
  __syncthreads();
  if (tid < 128) {
    int cl = tid >> 6;
    int cc = cc0 + cl;
    float p = 0.f;
#pragma unroll
    for (int i = 0; i < 8; ++i) p += red[i][cl][b];
    out[((size_t)b * NAHEAD + srow) * HDIM + cc] = p + b_fc[cc];
  }
}

__global__ __launch_bounds__(256)
void transpose_x(const float* __restrict__ x, float* __restrict__ xT)
{
  __shared__ float tile[64][65];
  const int t = blockIdx.x;
  const int lane = threadIdx.x & 63;
  const int w    = threadIdx.x >> 6;
#pragma unroll
  for (int ii = 0; ii < 16; ++ii) {
    int b = w * 16 + ii;
    tile[b][lane] = x[((size_t)b * TT + t) * IDIM + lane];
  }
  __syncthreads();
#pragma unroll
  for (int ii = 0; ii < 16; ++ii) {
    int i = w * 16 + ii;
    xT[((size_t)t * IDIM + i) * BATCH + lane] = tile[lane][i];
  }
}

// ---------------------------------------------------------------------------
extern "C" void kernel_launch(void* const* d_in, const int* in_sizes, int n_in,
                              void* d_out, int out_size, void* d_ws, size_t ws_size,
                              hipStream_t stream) {
  const float* x     = (const float*)d_in[0];
  const float* w_ih0 = (const float*)d_in[1];
  const float* w_hh0 = (const float*)d_in[2];
  const float* b_ih0 = (const float*)d_in[3];
  const float* b_hh0 = (const float*)d_in[4];
  const float* w_ih1 = (const float*)d_in[5];
  const float* w_hh1 = (const float*)d_in[6];
  const float* b_ih1 = (const float*)d_in[7];
  const float* b_hh1 = (const float*)d_in[8];
  const float* w_ihd = (const float*)d_in[9];
  const float* w_hhd = (const float*)d_in[10];
  const float* b_ihd = (const float*)d_in[11];
  const float* b_hhd = (const float*)d_in[12];
  const float* w_fc  = (const float*)d_in[13];
  const float* b_fc  = (const float*)d_in[14];
  float* out = (float*)d_out;

  char* ws = (char*)d_ws;
  size_t off = 0;
  auto alloc = [&](size_t bytes) -> void* {
    void* p = ws + off;
    off += (bytes + 255) & ~(size_t)255;
    return p;
  };

  float* cst0 = (float*)alloc((size_t)HB * 4);            // zero (fallback)
  float* cst1 = (float*)alloc((size_t)HB * 4);            // final L1 c-state
  float* seq0 = (float*)alloc((size_t)(TT + 1) * HB * 4); // slot0 zero
  float* enc  = (float*)alloc((size_t)(TT + 1) * HB * 4); // slot0 zero
  float* xT   = (float*)alloc((size_t)TT * IDIM * BATCH * 4);
  float* scores = (float*)alloc((size_t)TT * BATCH * 4);
  float* xi     = (float*)alloc((size_t)HB * 4);
  float* hdec   = (float*)alloc((size_t)2 * HB * 4);
  unsigned* flags   = (unsigned*)alloc(256 * 16 * 4);     // encoder barrier
  unsigned* release = (unsigned*)alloc(256);
  (void)ws_size; (void)in_sizes; (void)n_in; (void)out_size;

  hipMemsetAsync(cst0, 0, (size_t)HB * 4 * 2, stream);    // cst0+cst1
  hipMemsetAsync(seq0, 0, (size_t)HB * 4, stream);
  hipMemsetAsync(enc,  0, (size_t)HB * 4, stream);
  hipMemsetAsync(flags, 0, 256 * 16 * 4, stream);
  hipMemsetAsync(release, 0, 256, stream);

  transpose_x<<<TT, 256, 0, stream>>>(x, xT);

  static bool attr_set = false;
  if (!attr_set) {
    hipFuncSetAttribute(reinterpret_cast<const void*>(encoder_coop),
                        hipFuncAttributeMaxDynamicSharedMemorySize,
                        ENC_SMEM_BYTES);
    attr_set = true;
  }

  // ---- encoder: ONE cooperative kernel (round-6/9/12 verified config) ----
  void* args[] = {
    (void*)&xT,
    (void*)&w_ih0, (void*)&w_hh0, (void*)&b_ih0, (void*)&b_hh0,
    (void*)&w_ih1, (void*)&w_hh1, (void*)&b_ih1, (void*)&b_hh1,
    (void*)&seq0, (void*)&enc, (void*)&cst1, (void*)&flags, (void*)&release
  };
  hipError_t cerr = hipLaunchCooperativeKernel(
      reinterpret_cast<void*>(encoder_coop), dim3(256), dim3(1024),
      args, (unsigned)ENC_SMEM_BYTES, stream);
  if (cerr != hipSuccess) {
    for (int t = 0; t <= TT; ++t) {
      lstm_step<<<256, 1024, 0, stream>>>(
          t, xT, w_ih0, w_hh0, b_ih0, b_hh0,
          w_ih1, w_hh1, b_ih1, b_hh1, seq0, enc, cst0, cst1);
    }
  }

  // ---- decoder: launch-based chain (round-6/12 verified: ~0.75 ms; the
  // coop decoder measured 1.2-1.3 ms in rounds 8/9 — launches win here) ----
  const float* h_cur = enc + (size_t)TT * HB;
  for (int s = 0; s < NAHEAD; ++s) {
    attn_scores<<<256, 512, 0, stream>>>(enc, h_cur, scores);
    attn_ctx<<<256, 512, 0, stream>>>(enc, scores, h_cur, w_fc, b_fc,
                                      xi, out, s);
    float* h_nxt = hdec + (size_t)(s & 1) * HB;
    dec_gates<<<256, 1024, 0, stream>>>(xi, h_cur, w_ihd, w_hhd,
                                        b_ihd, b_hhd, cst1, h_nxt);
    h_cur = h_nxt;
  }
  fc_out<<<256, 512, 0, stream>>>(h_cur, w_fc, b_fc, out, NAHEAD - 1);
}